// Round 1
// baseline (480.567 us; speedup 1.0000x reference)
//
#include <hip/hip_runtime.h>
#include <cstdint>
#include <cstddef>

#define NB    2
#define N1    4096
#define N2    16384
#define CF    64
#define KNN   8
#define SPLIT 4
#define NS    (N1 / SPLIT)   // 1024 targets per split

// ---------------------------------------------------------------------------
// kernel 0: transpose feat1 [B,C,N1] -> feat1T [B,N1,C]; pack xyz1/flow float4
// ---------------------------------------------------------------------------
__global__ __launch_bounds__(256) void k_pack(
    const float* __restrict__ xyz1, const float* __restrict__ feat1,
    const float* __restrict__ flow,
    float* __restrict__ feat1T, float4* __restrict__ aux4,
    float4* __restrict__ flow4)
{
    __shared__ float tile[64][65];   // [c][n] padded -> conflict-free transpose
    const int b  = blockIdx.y;
    const int n0 = blockIdx.x * 64;
    const int tid = threadIdx.x;
    const int nl = tid & 63, cq = tid >> 6;

#pragma unroll
    for (int r = 0; r < 16; ++r) {
        const int c = r * 4 + cq;
        tile[c][nl] = feat1[((size_t)(b * CF + c)) * N1 + n0 + nl];
    }
    __syncthreads();
#pragma unroll
    for (int r = 0; r < 16; ++r) {
        const int nn = r * 4 + cq;
        feat1T[((size_t)(b * N1 + n0 + nn)) * CF + nl] = tile[nl][nn];
    }
    if (tid < 64) {
        const int n = n0 + tid;
        const float x = xyz1[(b * 3 + 0) * N1 + n];
        const float y = xyz1[(b * 3 + 1) * N1 + n];
        const float z = xyz1[(b * 3 + 2) * N1 + n];
        aux4[b * N1 + n] = make_float4(x, y, z, 0.f);
        const float fx = flow[(b * 3 + 0) * N1 + n];
        const float fy = flow[(b * 3 + 1) * N1 + n];
        const float fz = flow[(b * 3 + 2) * N1 + n];
        flow4[b * N1 + n] = make_float4(fx, fy, fz, 0.f);
    }
}

// ---------------------------------------------------------------------------
// kernel 1: partial KNN — each block scans one target split for 256 queries.
// Distance replicates reference fp32 rounding: d = (q2 + t2) - 2*qt, with
// qt = ((qx*tx + qy*ty) + qz*tz), all via _rn intrinsics (no fma contraction).
// ---------------------------------------------------------------------------
__global__ __launch_bounds__(256) void k_knn(
    const float* __restrict__ xyz1, const float* __restrict__ xyz2,
    float* __restrict__ partd, int* __restrict__ parti)
{
    __shared__ float4 pts[NS];  // {x, y, z, t2}
    const int b = blockIdx.z, sp = blockIdx.y;
    const int tid = threadIdx.x;

    for (int t = tid; t < NS; t += 256) {
        const int jg = sp * NS + t;
        const float x = xyz1[(b * 3 + 0) * N1 + jg];
        const float y = xyz1[(b * 3 + 1) * N1 + jg];
        const float z = xyz1[(b * 3 + 2) * N1 + jg];
        const float t2 = __fadd_rn(__fadd_rn(__fmul_rn(x, x), __fmul_rn(y, y)),
                                   __fmul_rn(z, z));
        pts[t] = make_float4(x, y, z, t2);
    }
    __syncthreads();

    const int n = blockIdx.x * 256 + tid;
    const float qx = xyz2[(b * 3 + 0) * N2 + n];
    const float qy = xyz2[(b * 3 + 1) * N2 + n];
    const float qz = xyz2[(b * 3 + 2) * N2 + n];
    const float q2 = __fadd_rn(__fadd_rn(__fmul_rn(qx, qx), __fmul_rn(qy, qy)),
                               __fmul_rn(qz, qz));

    float bd[KNN]; int bi[KNN];
#pragma unroll
    for (int r = 0; r < KNN; ++r) { bd[r] = INFINITY; bi[r] = 0; }

#pragma unroll 4
    for (int j = 0; j < NS; ++j) {
        const float4 p = pts[j];
        const float qt = __fadd_rn(
            __fadd_rn(__fmul_rn(qx, p.x), __fmul_rn(qy, p.y)),
            __fmul_rn(qz, p.z));
        const float d = __fsub_rn(__fadd_rn(q2, p.w), __fadd_rn(qt, qt));
        if (d < bd[KNN - 1]) {               // strict < : ties keep lower index
            bd[KNN - 1] = d; bi[KNN - 1] = sp * NS + j;
#pragma unroll
            for (int s = KNN - 1; s > 0; --s) {
                if (bd[s] < bd[s - 1]) {     // stable bubble-up
                    const float td = bd[s]; bd[s] = bd[s - 1]; bd[s - 1] = td;
                    const int   ti = bi[s]; bi[s] = bi[s - 1]; bi[s - 1] = ti;
                }
            }
        }
    }

    const size_t qi = (size_t)b * N2 + n;
    float* pd = partd + (qi * SPLIT + sp) * KNN;
    int*   pi = parti + (qi * SPLIT + sp) * KNN;
#pragma unroll
    for (int r = 0; r < KNN; ++r) { pd[r] = bd[r]; pi[r] = bi[r]; }
}

// ---------------------------------------------------------------------------
// kernel 2: merge SPLIT partial top-8 lists (processed in ascending index
// order -> stable ties, matches jax.lax.top_k)
// ---------------------------------------------------------------------------
__global__ __launch_bounds__(256) void k_merge(
    const float* __restrict__ partd, const int* __restrict__ parti,
    int* __restrict__ knn_idx)
{
    const int q = blockIdx.x * 256 + threadIdx.x;
    const float* pd = partd + (size_t)q * SPLIT * KNN;
    const int*   pi = parti + (size_t)q * SPLIT * KNN;

    float bd[KNN]; int bi[KNN];
#pragma unroll
    for (int r = 0; r < KNN; ++r) { bd[r] = INFINITY; bi[r] = 0; }

#pragma unroll
    for (int t = 0; t < SPLIT * KNN; ++t) {
        const float d = pd[t]; const int i = pi[t];
        if (d < bd[KNN - 1]) {
            bd[KNN - 1] = d; bi[KNN - 1] = i;
#pragma unroll
            for (int s = KNN - 1; s > 0; --s) {
                if (bd[s] < bd[s - 1]) {
                    const float td = bd[s]; bd[s] = bd[s - 1]; bd[s - 1] = td;
                    const int   ti = bi[s]; bi[s] = bi[s - 1]; bi[s - 1] = ti;
                }
            }
        }
    }
#pragma unroll
    for (int r = 0; r < KNN; ++r) knn_idx[(size_t)q * KNN + r] = bi[r];
}

// ---------------------------------------------------------------------------
// kernel 3: gather + MLP + softmax + weighted flow sum. One wave per query,
// lane = output channel of layer 1. W1 staged in LDS (row stride 68, b128).
// ---------------------------------------------------------------------------
__global__ __launch_bounds__(256) void k_mlp(
    const float* __restrict__ feat1T, const float4* __restrict__ aux4,
    const float4* __restrict__ flow4, const int* __restrict__ knn_idx,
    const float* __restrict__ xyz2,
    const float* __restrict__ W1, const float* __restrict__ b1,
    const float* __restrict__ W2, const float* __restrict__ b2,
    float* __restrict__ out)
{
    constexpr int QPW = 8;   // queries per wave
    __shared__ __align__(16) float w1s[64 * 68];
    __shared__ __align__(16) float inbuf[4][8][68];
    __shared__ __align__(16) float4 flbuf[4][8];

    const int tid = threadIdx.x;
    const int wave = tid >> 6, lane = tid & 63;

    for (int t = tid; t < 64 * 67; t += 256) {
        const int o = t / 67, c = t - o * 67;
        w1s[o * 68 + c] = W1[t];
    }
    if (tid < 64) w1s[tid * 68 + 67] = 0.f;

    const float b1v = b1[lane];
    const float w2a = W2[lane], w2b = W2[64 + lane], w2c = W2[128 + lane];
    const float b20 = b2[0], b21 = b2[1], b22 = b2[2];
    __syncthreads();

    const int k = lane >> 3, p = lane & 7;
    const float* flf = (const float*)&flbuf[wave][0];

    for (int it = 0; it < QPW; ++it) {
        const int q = blockIdx.x * (4 * QPW) + wave * QPW + it;
        const int b = q >> 14, n = q & (N2 - 1);
        __syncthreads();   // protect inbuf/flbuf reuse across iterations

        const int idk = knn_idx[(size_t)q * KNN + k];
        const float4* frow = (const float4*)(feat1T + ((size_t)(b * N1 + idk)) * CF);
        const float4 v0 = frow[p * 2], v1 = frow[p * 2 + 1];
        float4* drow = (float4*)(&inbuf[wave][k][0]);
        drow[p * 2] = v0; drow[p * 2 + 1] = v1;
        if (p == 0) {
            const float4 ax = aux4[b * N1 + idk];
            inbuf[wave][k][64] = ax.x - xyz2[(b * 3 + 0) * N2 + n];
            inbuf[wave][k][65] = ax.y - xyz2[(b * 3 + 1) * N2 + n];
            inbuf[wave][k][66] = ax.z - xyz2[(b * 3 + 2) * N2 + n];
            inbuf[wave][k][67] = 0.f;
        }
        if (p == 1) flbuf[wave][k] = flow4[b * N1 + idk];
        __syncthreads();

        // layer 1: h[kk] = b1 + W1[lane,:] . in[kk,:]
        float h[8];
#pragma unroll
        for (int kk = 0; kk < 8; ++kk) h[kk] = b1v;
#pragma unroll
        for (int c4 = 0; c4 < 17; ++c4) {
            const float4 wv = *(const float4*)(&w1s[lane * 68 + c4 * 4]);
#pragma unroll
            for (int kk = 0; kk < 8; ++kk) {
                const float4 iv = *(const float4*)(&inbuf[wave][kk][c4 * 4]);
                h[kk] = fmaf(wv.x, iv.x, h[kk]);
                h[kk] = fmaf(wv.y, iv.y, h[kk]);
                h[kk] = fmaf(wv.z, iv.z, h[kk]);
                h[kk] = fmaf(wv.w, iv.w, h[kk]);
            }
        }

        // leaky relu + layer 2 (3x64 dot via butterfly reduction over lanes)
        float s0[8], s1[8], s2[8];
#pragma unroll
        for (int kk = 0; kk < 8; ++kk) {
            float hv = h[kk];
            hv = hv >= 0.f ? hv : 0.1f * hv;
            float p0 = w2a * hv, p1 = w2b * hv, p2 = w2c * hv;
#pragma unroll
            for (int off = 32; off > 0; off >>= 1) {
                p0 += __shfl_xor(p0, off, 64);
                p1 += __shfl_xor(p1, off, 64);
                p2 += __shfl_xor(p2, off, 64);
            }
            s0[kk] = p0 + b20; s1[kk] = p1 + b21; s2[kk] = p2 + b22;
        }

        // softmax over k per channel + weighted flow sum (redundant per lane)
        float res0, res1, res2;
        {
            float m = s0[0];
#pragma unroll
            for (int kk = 1; kk < 8; ++kk) m = fmaxf(m, s0[kk]);
            float S = 0.f, acc = 0.f;
#pragma unroll
            for (int kk = 0; kk < 8; ++kk) {
                const float e = __expf(s0[kk] - m);
                S += e; acc = fmaf(flf[kk * 4 + 0], e, acc);
            }
            res0 = acc / S;
        }
        {
            float m = s1[0];
#pragma unroll
            for (int kk = 1; kk < 8; ++kk) m = fmaxf(m, s1[kk]);
            float S = 0.f, acc = 0.f;
#pragma unroll
            for (int kk = 0; kk < 8; ++kk) {
                const float e = __expf(s1[kk] - m);
                S += e; acc = fmaf(flf[kk * 4 + 1], e, acc);
            }
            res1 = acc / S;
        }
        {
            float m = s2[0];
#pragma unroll
            for (int kk = 1; kk < 8; ++kk) m = fmaxf(m, s2[kk]);
            float S = 0.f, acc = 0.f;
#pragma unroll
            for (int kk = 0; kk < 8; ++kk) {
                const float e = __expf(s2[kk] - m);
                S += e; acc = fmaf(flf[kk * 4 + 2], e, acc);
            }
            res2 = acc / S;
        }

        const float resv = lane == 0 ? res0 : (lane == 1 ? res1 : res2);
        if (lane < 3) out[((size_t)(b * 3 + lane)) * N2 + n] = resv;
    }
}

// ---------------------------------------------------------------------------
extern "C" void kernel_launch(void* const* d_in, const int* in_sizes, int n_in,
                              void* d_out, int out_size, void* d_ws, size_t ws_size,
                              hipStream_t stream)
{
    const float* xyz1  = (const float*)d_in[0];
    const float* xyz2  = (const float*)d_in[1];
    const float* feat1 = (const float*)d_in[2];
    const float* flow  = (const float*)d_in[3];
    const float* W1    = (const float*)d_in[4];
    const float* b1    = (const float*)d_in[5];
    const float* W2    = (const float*)d_in[6];
    const float* b2    = (const float*)d_in[7];
    float* out = (float*)d_out;

    char* ws = (char*)d_ws;
    float*  feat1T  = (float*)(ws);                                   // 2 MB
    float4* aux4    = (float4*)(ws + (2u << 20));                     // 128 KB
    float4* flow4   = (float4*)(ws + (2u << 20) + (128u << 10));      // 128 KB
    int*    knn_idx = (int*)  (ws + (2u << 20) + (256u << 10));       // 1 MB
    float*  partd   = (float*)(ws + (3u << 20) + (256u << 10));       // 4 MB
    int*    parti   = (int*)  (ws + (7u << 20) + (256u << 10));       // 4 MB

    hipLaunchKernelGGL(k_pack, dim3(N1 / 64, NB), dim3(256), 0, stream,
                       xyz1, feat1, flow, feat1T, aux4, flow4);
    hipLaunchKernelGGL(k_knn, dim3(N2 / 256, SPLIT, NB), dim3(256), 0, stream,
                       xyz1, xyz2, partd, parti);
    hipLaunchKernelGGL(k_merge, dim3(NB * N2 / 256), dim3(256), 0, stream,
                       partd, parti, knn_idx);
    hipLaunchKernelGGL(k_mlp, dim3(NB * N2 / 32), dim3(256), 0, stream,
                       feat1T, aux4, flow4, knn_idx, xyz2, W1, b1, W2, b2, out);
}

// Round 2
// 448.694 us; speedup vs baseline: 1.0710x; 1.0710x over previous
//
#include <hip/hip_runtime.h>
#include <cstdint>
#include <cstddef>

#define NB    2
#define N1    4096
#define N2    16384
#define CF    64
#define KNN   8

// ---------------------------------------------------------------------------
// kernel 0: transpose feat1 [B,C,N1] -> feat1T [B,N1,C]; pack xyz1/flow float4
// ---------------------------------------------------------------------------
__global__ __launch_bounds__(256) void k_pack(
    const float* __restrict__ xyz1, const float* __restrict__ feat1,
    const float* __restrict__ flow,
    float* __restrict__ feat1T, float4* __restrict__ aux4,
    float4* __restrict__ flow4)
{
    __shared__ float tile[64][65];   // [c][n] padded -> conflict-free transpose
    const int b  = blockIdx.y;
    const int n0 = blockIdx.x * 64;
    const int tid = threadIdx.x;
    const int nl = tid & 63, cq = tid >> 6;

#pragma unroll
    for (int r = 0; r < 16; ++r) {
        const int c = r * 4 + cq;
        tile[c][nl] = feat1[((size_t)(b * CF + c)) * N1 + n0 + nl];
    }
    __syncthreads();
#pragma unroll
    for (int r = 0; r < 16; ++r) {
        const int nn = r * 4 + cq;
        feat1T[((size_t)(b * N1 + n0 + nn)) * CF + nl] = tile[nl][nn];
    }
    if (tid < 64) {
        const int n = n0 + tid;
        const float x = xyz1[(b * 3 + 0) * N1 + n];
        const float y = xyz1[(b * 3 + 1) * N1 + n];
        const float z = xyz1[(b * 3 + 2) * N1 + n];
        aux4[b * N1 + n] = make_float4(x, y, z, 0.f);
        const float fx = flow[(b * 3 + 0) * N1 + n];
        const float fy = flow[(b * 3 + 1) * N1 + n];
        const float fz = flow[(b * 3 + 2) * N1 + n];
        flow4[b * N1 + n] = make_float4(fx, fy, fz, 0.f);
    }
}

// ---------------------------------------------------------------------------
// branchless stable top-8 insert. bd ascending; c[s] monotone in s, so every
// position updates independently (flat ~2-op dep chain, no serial bubble-up).
// Strict < keeps the earlier (lower-index) entry on ties, matching top_k.
// ---------------------------------------------------------------------------
__device__ __forceinline__ void topk_insert(float (&bd)[KNN], int (&bi)[KNN],
                                            const float d, const int idx)
{
    const bool c0 = d < bd[0], c1 = d < bd[1], c2 = d < bd[2], c3 = d < bd[3];
    const bool c4 = d < bd[4], c5 = d < bd[5], c6 = d < bd[6], c7 = d < bd[7];
    // update downward: each step reads the ORIGINAL bd[s-1]
    bd[7] = c6 ? bd[6] : (c7 ? d : bd[7]);  bi[7] = c6 ? bi[6] : (c7 ? idx : bi[7]);
    bd[6] = c5 ? bd[5] : (c6 ? d : bd[6]);  bi[6] = c5 ? bi[5] : (c6 ? idx : bi[6]);
    bd[5] = c4 ? bd[4] : (c5 ? d : bd[5]);  bi[5] = c4 ? bi[4] : (c5 ? idx : bi[5]);
    bd[4] = c3 ? bd[3] : (c4 ? d : bd[4]);  bi[4] = c3 ? bi[3] : (c4 ? idx : bi[4]);
    bd[3] = c2 ? bd[2] : (c3 ? d : bd[3]);  bi[3] = c2 ? bi[2] : (c3 ? idx : bi[3]);
    bd[2] = c1 ? bd[1] : (c2 ? d : bd[2]);  bi[2] = c1 ? bi[1] : (c2 ? idx : bi[2]);
    bd[1] = c0 ? bd[0] : (c1 ? d : bd[1]);  bi[1] = c0 ? bi[0] : (c1 ? idx : bi[1]);
    bd[0] = c0 ? d : bd[0];                 bi[0] = c0 ? idx : bi[0];
}

// ---------------------------------------------------------------------------
// kernel 1: partial KNN. QPT=2 queries/thread (ILP + LDS-read amortization),
// branchless insert. Distance replicates reference fp32 rounding exactly:
// d = (q2 + t2) - (qt + qt), qt = ((qx*tx + qy*ty) + qz*tz), all _rn.
// ---------------------------------------------------------------------------
template <int NS_>
__global__ __launch_bounds__(256) void k_knn2(
    const float* __restrict__ xyz1, const float* __restrict__ xyz2,
    float* __restrict__ partd, int* __restrict__ parti)
{
    constexpr int SPLIT_ = N1 / NS_;
    __shared__ float4 pts[NS_];  // {x, y, z, t2}
    const int sp  = blockIdx.y;
    const int tid = threadIdx.x;
    const int q0  = blockIdx.x * 512 + tid;   // block covers 512 query slots
    const int q1  = q0 + 256;
    const int b   = q0 >> 14;                  // uniform per block (512 | 16384)

    for (int t = tid; t < NS_; t += 256) {
        const int jg = sp * NS_ + t;
        const float x = xyz1[(b * 3 + 0) * N1 + jg];
        const float y = xyz1[(b * 3 + 1) * N1 + jg];
        const float z = xyz1[(b * 3 + 2) * N1 + jg];
        const float t2 = __fadd_rn(__fadd_rn(__fmul_rn(x, x), __fmul_rn(y, y)),
                                   __fmul_rn(z, z));
        pts[t] = make_float4(x, y, z, t2);
    }
    __syncthreads();

    const int n0 = q0 & (N2 - 1), n1 = n0 + 256;
    const float ax = xyz2[(b * 3 + 0) * N2 + n0];
    const float ay = xyz2[(b * 3 + 1) * N2 + n0];
    const float az = xyz2[(b * 3 + 2) * N2 + n0];
    const float a2 = __fadd_rn(__fadd_rn(__fmul_rn(ax, ax), __fmul_rn(ay, ay)),
                               __fmul_rn(az, az));
    const float cx = xyz2[(b * 3 + 0) * N2 + n1];
    const float cy = xyz2[(b * 3 + 1) * N2 + n1];
    const float cz = xyz2[(b * 3 + 2) * N2 + n1];
    const float c2 = __fadd_rn(__fadd_rn(__fmul_rn(cx, cx), __fmul_rn(cy, cy)),
                               __fmul_rn(cz, cz));

    float bdA[KNN], bdB[KNN]; int biA[KNN], biB[KNN];
#pragma unroll
    for (int r = 0; r < KNN; ++r) {
        bdA[r] = INFINITY; biA[r] = 0; bdB[r] = INFINITY; biB[r] = 0;
    }

#pragma unroll 4
    for (int j = 0; j < NS_; ++j) {
        const float4 p = pts[j];
        const int idx = sp * NS_ + j;
        const float qtA = __fadd_rn(
            __fadd_rn(__fmul_rn(ax, p.x), __fmul_rn(ay, p.y)),
            __fmul_rn(az, p.z));
        const float dA = __fsub_rn(__fadd_rn(a2, p.w), __fadd_rn(qtA, qtA));
        const float qtB = __fadd_rn(
            __fadd_rn(__fmul_rn(cx, p.x), __fmul_rn(cy, p.y)),
            __fmul_rn(cz, p.z));
        const float dB = __fsub_rn(__fadd_rn(c2, p.w), __fadd_rn(qtB, qtB));
        topk_insert(bdA, biA, dA, idx);
        topk_insert(bdB, biB, dB, idx);
    }

    {
        float* pd = partd + ((size_t)q0 * SPLIT_ + sp) * KNN;
        int*   pi = parti + ((size_t)q0 * SPLIT_ + sp) * KNN;
#pragma unroll
        for (int r = 0; r < KNN; ++r) { pd[r] = bdA[r]; pi[r] = biA[r]; }
    }
    {
        float* pd = partd + ((size_t)q1 * SPLIT_ + sp) * KNN;
        int*   pi = parti + ((size_t)q1 * SPLIT_ + sp) * KNN;
#pragma unroll
        for (int r = 0; r < KNN; ++r) { pd[r] = bdB[r]; pi[r] = biB[r]; }
    }
}

// ---------------------------------------------------------------------------
// kernel 2: merge partial top-8 lists (ascending split order -> stable ties)
// ---------------------------------------------------------------------------
template <int SPLIT_>
__global__ __launch_bounds__(256) void k_merge2(
    const float* __restrict__ partd, const int* __restrict__ parti,
    int* __restrict__ knn_idx)
{
    const int q = blockIdx.x * 256 + threadIdx.x;
    const float* pd = partd + (size_t)q * SPLIT_ * KNN;
    const int*   pi = parti + (size_t)q * SPLIT_ * KNN;

    float bd[KNN]; int bi[KNN];
#pragma unroll
    for (int r = 0; r < KNN; ++r) { bd[r] = INFINITY; bi[r] = 0; }

#pragma unroll
    for (int t = 0; t < SPLIT_ * KNN; ++t)
        topk_insert(bd, bi, pd[t], pi[t]);

#pragma unroll
    for (int r = 0; r < KNN; ++r) knn_idx[(size_t)q * KNN + r] = bi[r];
}

// ---------------------------------------------------------------------------
// kernel 3: gather + MLP + softmax + weighted flow sum (unchanged this round)
// ---------------------------------------------------------------------------
__global__ __launch_bounds__(256) void k_mlp(
    const float* __restrict__ feat1T, const float4* __restrict__ aux4,
    const float4* __restrict__ flow4, const int* __restrict__ knn_idx,
    const float* __restrict__ xyz2,
    const float* __restrict__ W1, const float* __restrict__ b1,
    const float* __restrict__ W2, const float* __restrict__ b2,
    float* __restrict__ out)
{
    constexpr int QPW = 8;   // queries per wave
    __shared__ __align__(16) float w1s[64 * 68];
    __shared__ __align__(16) float inbuf[4][8][68];
    __shared__ __align__(16) float4 flbuf[4][8];

    const int tid = threadIdx.x;
    const int wave = tid >> 6, lane = tid & 63;

    for (int t = tid; t < 64 * 67; t += 256) {
        const int o = t / 67, c = t - o * 67;
        w1s[o * 68 + c] = W1[t];
    }
    if (tid < 64) w1s[tid * 68 + 67] = 0.f;

    const float b1v = b1[lane];
    const float w2a = W2[lane], w2b = W2[64 + lane], w2c = W2[128 + lane];
    const float b20 = b2[0], b21 = b2[1], b22 = b2[2];
    __syncthreads();

    const int k = lane >> 3, p = lane & 7;
    const float* flf = (const float*)&flbuf[wave][0];

    for (int it = 0; it < QPW; ++it) {
        const int q = blockIdx.x * (4 * QPW) + wave * QPW + it;
        const int b = q >> 14, n = q & (N2 - 1);
        __syncthreads();   // protect inbuf/flbuf reuse across iterations

        const int idk = knn_idx[(size_t)q * KNN + k];
        const float4* frow = (const float4*)(feat1T + ((size_t)(b * N1 + idk)) * CF);
        const float4 v0 = frow[p * 2], v1 = frow[p * 2 + 1];
        float4* drow = (float4*)(&inbuf[wave][k][0]);
        drow[p * 2] = v0; drow[p * 2 + 1] = v1;
        if (p == 0) {
            const float4 ax = aux4[b * N1 + idk];
            inbuf[wave][k][64] = ax.x - xyz2[(b * 3 + 0) * N2 + n];
            inbuf[wave][k][65] = ax.y - xyz2[(b * 3 + 1) * N2 + n];
            inbuf[wave][k][66] = ax.z - xyz2[(b * 3 + 2) * N2 + n];
            inbuf[wave][k][67] = 0.f;
        }
        if (p == 1) flbuf[wave][k] = flow4[b * N1 + idk];
        __syncthreads();

        float h[8];
#pragma unroll
        for (int kk = 0; kk < 8; ++kk) h[kk] = b1v;
#pragma unroll
        for (int c4 = 0; c4 < 17; ++c4) {
            const float4 wv = *(const float4*)(&w1s[lane * 68 + c4 * 4]);
#pragma unroll
            for (int kk = 0; kk < 8; ++kk) {
                const float4 iv = *(const float4*)(&inbuf[wave][kk][c4 * 4]);
                h[kk] = fmaf(wv.x, iv.x, h[kk]);
                h[kk] = fmaf(wv.y, iv.y, h[kk]);
                h[kk] = fmaf(wv.z, iv.z, h[kk]);
                h[kk] = fmaf(wv.w, iv.w, h[kk]);
            }
        }

        float s0[8], s1[8], s2[8];
#pragma unroll
        for (int kk = 0; kk < 8; ++kk) {
            float hv = h[kk];
            hv = hv >= 0.f ? hv : 0.1f * hv;
            float p0 = w2a * hv, p1 = w2b * hv, p2 = w2c * hv;
#pragma unroll
            for (int off = 32; off > 0; off >>= 1) {
                p0 += __shfl_xor(p0, off, 64);
                p1 += __shfl_xor(p1, off, 64);
                p2 += __shfl_xor(p2, off, 64);
            }
            s0[kk] = p0 + b20; s1[kk] = p1 + b21; s2[kk] = p2 + b22;
        }

        float res0, res1, res2;
        {
            float m = s0[0];
#pragma unroll
            for (int kk = 1; kk < 8; ++kk) m = fmaxf(m, s0[kk]);
            float S = 0.f, acc = 0.f;
#pragma unroll
            for (int kk = 0; kk < 8; ++kk) {
                const float e = __expf(s0[kk] - m);
                S += e; acc = fmaf(flf[kk * 4 + 0], e, acc);
            }
            res0 = acc / S;
        }
        {
            float m = s1[0];
#pragma unroll
            for (int kk = 1; kk < 8; ++kk) m = fmaxf(m, s1[kk]);
            float S = 0.f, acc = 0.f;
#pragma unroll
            for (int kk = 0; kk < 8; ++kk) {
                const float e = __expf(s1[kk] - m);
                S += e; acc = fmaf(flf[kk * 4 + 1], e, acc);
            }
            res1 = acc / S;
        }
        {
            float m = s2[0];
#pragma unroll
            for (int kk = 1; kk < 8; ++kk) m = fmaxf(m, s2[kk]);
            float S = 0.f, acc = 0.f;
#pragma unroll
            for (int kk = 0; kk < 8; ++kk) {
                const float e = __expf(s2[kk] - m);
                S += e; acc = fmaf(flf[kk * 4 + 2], e, acc);
            }
            res2 = acc / S;
        }

        const float resv = lane == 0 ? res0 : (lane == 1 ? res1 : res2);
        if (lane < 3) out[((size_t)(b * 3 + lane)) * N2 + n] = resv;
    }
}

// ---------------------------------------------------------------------------
extern "C" void kernel_launch(void* const* d_in, const int* in_sizes, int n_in,
                              void* d_out, int out_size, void* d_ws, size_t ws_size,
                              hipStream_t stream)
{
    const float* xyz1  = (const float*)d_in[0];
    const float* xyz2  = (const float*)d_in[1];
    const float* feat1 = (const float*)d_in[2];
    const float* flow  = (const float*)d_in[3];
    const float* W1    = (const float*)d_in[4];
    const float* b1    = (const float*)d_in[5];
    const float* W2    = (const float*)d_in[6];
    const float* b2    = (const float*)d_in[7];
    float* out = (float*)d_out;

    char* ws = (char*)d_ws;
    float*  feat1T  = (float*)(ws);                                   // 2 MiB
    float4* aux4    = (float4*)(ws + (2u << 20));                     // 128 KiB
    float4* flow4   = (float4*)(ws + (2u << 20) + (128u << 10));      // 128 KiB
    int*    knn_idx = (int*)  (ws + (2u << 20) + (256u << 10));       // 1 MiB
    char*   part0   = ws + (3u << 20) + (256u << 10);

    // partd/parti each = SPLIT MiB (32768 q x 8 x 4 B per split)
    const size_t need8 = (size_t)(3u << 20) + (256u << 10) + 2 * 8 * (1u << 20);
    const bool   big   = ws_size >= need8;

    hipLaunchKernelGGL(k_pack, dim3(N1 / 64, NB), dim3(256), 0, stream,
                       xyz1, feat1, flow, feat1T, aux4, flow4);

    if (big) {
        float* partd = (float*)part0;
        int*   parti = (int*)(part0 + (size_t)8 * (1u << 20));
        hipLaunchKernelGGL((k_knn2<512>), dim3(NB * N2 / 512, 8), dim3(256),
                           0, stream, xyz1, xyz2, partd, parti);
        hipLaunchKernelGGL((k_merge2<8>), dim3(NB * N2 / 256), dim3(256),
                           0, stream, partd, parti, knn_idx);
    } else {
        float* partd = (float*)part0;
        int*   parti = (int*)(part0 + (size_t)4 * (1u << 20));
        hipLaunchKernelGGL((k_knn2<1024>), dim3(NB * N2 / 512, 4), dim3(256),
                           0, stream, xyz1, xyz2, partd, parti);
        hipLaunchKernelGGL((k_merge2<4>), dim3(NB * N2 / 256), dim3(256),
                           0, stream, partd, parti, knn_idx);
    }

    hipLaunchKernelGGL(k_mlp, dim3(NB * N2 / 32), dim3(256), 0, stream,
                       feat1T, aux4, flow4, knn_idx, xyz2, W1, b1, W2, b2, out);
}